// Round 2
// baseline (3946.413 us; speedup 1.0000x reference)
//
#include <hip/hip_runtime.h>
#include <hip/hip_fp16.h>
#include <cstdint>

typedef _Float16 half8 __attribute__((ext_vector_type(8)));
typedef float f32x4 __attribute__((ext_vector_type(4)));

#define MFMA_F16 __builtin_amdgcn_mfma_f32_16x16x32_f16

__device__ __forceinline__ float fast_rcp(float x){
#if __has_builtin(__builtin_amdgcn_rcpf)
  return __builtin_amdgcn_rcpf(x);
#else
  return 1.0f/x;
#endif
}
__device__ __forceinline__ float fast_exp2(float x){
#if __has_builtin(__builtin_amdgcn_exp2f)
  return __builtin_amdgcn_exp2f(x);
#else
  return exp2f(x);
#endif
}
__device__ __forceinline__ float sigm_f(float x){
  return fast_rcp(1.0f + fast_exp2(-1.44269504f*x));
}
__device__ __forceinline__ float tanh_fast(float x){
  float e = fast_exp2(-2.88539008f*x);            // e^(-2x)
  return fmaf(2.0f, fast_rcp(1.0f + e), -1.0f);   // 2/(1+e) - 1
}

// ---------------------------------------------------------------------------
// Phase A1: per-matrix max|w| (4 matrices of 768x256), atomicMax on int-punned
// non-negative floats. slots may be poison (0xAAAAAAAA = negative int) — fine.
// ---------------------------------------------------------------------------
__global__ __launch_bounds__(256) void k_maxabs(
    const float* __restrict__ w0, const float* __restrict__ w1,
    const float* __restrict__ w2, const float* __restrict__ w3,
    int n, int* __restrict__ slots)
{
  const float* srcs[4] = {w0, w1, w2, w3};
  int m    = blockIdx.x >> 5;   // 32 blocks per matrix
  int part = blockIdx.x & 31;
  const float* w = srcs[m];
  float loc = 0.0f;
  for (int i = part*256 + threadIdx.x; i < n; i += 32*256)
    loc = fmaxf(loc, fabsf(w[i]));
  for (int off = 32; off; off >>= 1)
    loc = fmaxf(loc, __shfl_down(loc, off, 64));
  __shared__ float red[4];
  int wv = threadIdx.x >> 6;
  if ((threadIdx.x & 63) == 0) red[wv] = loc;
  __syncthreads();
  if (threadIdx.x == 0) {
    float mx = fmaxf(fmaxf(red[0], red[1]), fmaxf(red[2], red[3]));
    atomicMax(&slots[m], __float_as_int(mx));
  }
}

// ---------------------------------------------------------------------------
// Phase A2: fake-quantize (rint(w/s)*s, s = max/127) -> fp16, written in
// MFMA-B-fragment-swizzled layout:
//   tile = g>>4, kb = k>>5, lane = ((k>>3)&3)*16 + (g&15), j = k&7
//   offset = (tile*8+kb)*512 + lane*8 + j     (half elements)
// ---------------------------------------------------------------------------
__global__ __launch_bounds__(256) void k_quant(
    const float* __restrict__ w0, const float* __restrict__ w1,
    const float* __restrict__ w2, const float* __restrict__ w3,
    const int* __restrict__ slots,
    _Float16* __restrict__ f0, _Float16* __restrict__ f1,
    _Float16* __restrict__ f2, _Float16* __restrict__ f3)
{
  const float* srcs[4] = {w0, w1, w2, w3};
  _Float16*    dsts[4] = {f0, f1, f2, f3};
  int idx = blockIdx.x*256 + threadIdx.x;       // 0 .. 786431
  int m = idx / 196608;
  int e = idx - m*196608;
  float scale = __int_as_float(slots[m]) * (1.0f/127.0f);
  float w = srcs[m][e];
  float q = rintf(w/scale) * scale;
  int g = e >> 8, k = e & 255;
  int tile = g >> 4, kb = k >> 5;
  int lane = ((k >> 3) & 3)*16 + (g & 15);
  int off  = (tile*8 + kb)*512 + lane*8 + (k & 7);
  dsts[m][off] = (_Float16)q;
}

// ---------------------------------------------------------------------------
// Fat GEMM: out[r][g] = sum_k A[r][k] * Wq[g][k] + bias[g], fp16 out.
// A: [R x 256] (f32 or fp16), Wf frag-swizzled fp16, R multiple of 64.
// Block = 256 thr (4 waves); tile = 64 rows x 128 cols; K=256 fully LDS-staged.
// ---------------------------------------------------------------------------
template<bool INF16>
__global__ __launch_bounds__(256) void k_gemm(
    const void* __restrict__ Ain, const _Float16* __restrict__ Wf,
    const float* __restrict__ bias, _Float16* __restrict__ out)
{
  __shared__ _Float16 Al[16384];                // 4 bands x 8 kb x 512 halves
  const int tid = threadIdx.x;
  const long r0 = (long)blockIdx.x * 64;
  const int by  = blockIdx.y;                   // 6 col-blocks of 128

  if (!INF16) {
    const float4* A = (const float4*)Ain;       // 64 float4 per row
    #pragma unroll
    for (int p = 0; p < 16; p++) {
      int n = p*256 + tid;                      // 0..4095 float4s
      int row = n >> 6, f4 = n & 63, k0 = f4*4;
      float4 v = A[(r0 + row)*64 + f4];
      int lane = ((k0 >> 3) & 3)*16 + (row & 15);
      _Float16* d = &Al[((row >> 4)*8 + (k0 >> 5))*512 + lane*8 + (k0 & 7)];
      d[0] = (_Float16)v.x; d[1] = (_Float16)v.y;
      d[2] = (_Float16)v.z; d[3] = (_Float16)v.w;
    }
  } else {
    const ushort4* A = (const ushort4*)Ain;     // 64 ushort4 per row (4 halves)
    #pragma unroll
    for (int p = 0; p < 16; p++) {
      int n = p*256 + tid;
      int row = n >> 6, f4 = n & 63, k0 = f4*4;
      ushort4 v = A[(r0 + row)*64 + f4];
      int lane = ((k0 >> 3) & 3)*16 + (row & 15);
      unsigned short* d = (unsigned short*)
          &Al[((row >> 4)*8 + (k0 >> 5))*512 + lane*8 + (k0 & 7)];
      d[0] = v.x; d[1] = v.y; d[2] = v.z; d[3] = v.w;
    }
  }
  __syncthreads();

  const int w = tid >> 6, l = tid & 63, q = l >> 4, c16 = l & 15;
  f32x4 acc[8];
  #pragma unroll
  for (int nt = 0; nt < 8; nt++) acc[nt] = (f32x4){0.f, 0.f, 0.f, 0.f};
  float bv[8];
  #pragma unroll
  for (int nt = 0; nt < 8; nt++) bv[nt] = bias[by*128 + nt*16 + c16];

  #pragma unroll
  for (int kb = 0; kb < 8; kb++) {
    half8 a = *(const half8*)&Al[(w*8 + kb)*512 + l*8];
    #pragma unroll
    for (int nt = 0; nt < 8; nt++) {
      half8 b = *(const half8*)&Wf[((size_t)((by*8 + nt)*8 + kb))*512 + l*8];
      acc[nt] = MFMA_F16(a, b, acc[nt], 0, 0, 0);
    }
  }

  #pragma unroll
  for (int nt = 0; nt < 8; nt++) {
    int colg = by*128 + nt*16 + c16;
    #pragma unroll
    for (int i = 0; i < 4; i++) {
      long rowg = r0 + w*16 + q*4 + i;
      out[(size_t)rowg*768 + colg] = (_Float16)(acc[nt][i] + bv[nt]);
    }
  }
}

// ---------------------------------------------------------------------------
// Serial GRU phase: 16 blocks x 1024 thr. Block handles batch rows b0..b0+15.
// Per step: gh = h @ Wq_hhT (fp16 MFMA), gates, h' -> LDS (frag order, dbuf).
// gi already contains x@W_ihT + b_ih. Wave w owns gate cols j=16w..16w+15
// (tiles w / 16+w / 32+w for r/z/n). One barrier per step.
// ---------------------------------------------------------------------------
__global__ __launch_bounds__(1024) void k_gru(
    const _Float16* __restrict__ gi, const _Float16* __restrict__ Wf,
    const float* __restrict__ bhh, float* __restrict__ hcarry,
    _Float16* __restrict__ hseq, int Csteps)
{
  __shared__ _Float16 hl[2][4096];              // 2 x 8KB frag-ordered h
  const int tid = threadIdx.x;
  const int b0  = blockIdx.x * 16;

  { // stage initial h (f32 carry -> fp16 frags)
    int n = tid*4;                              // 4096 halves total
    int b = n >> 8, k = n & 255;
    float4 v = *(const float4*)&hcarry[(size_t)(b0 + b)*256 + k];
    _Float16* d = &hl[0][(k >> 5)*512 + (((k >> 3) & 3)*16 + b)*8 + (k & 7)];
    d[0] = (_Float16)v.x; d[1] = (_Float16)v.y;
    d[2] = (_Float16)v.z; d[3] = (_Float16)v.w;
  }

  const int w = tid >> 6, l = tid & 63, q = l >> 4, c16 = l & 15;
  const int j = w*16 + c16;                     // gate column owned by lane
  const float bR = bhh[j], bZ = bhh[256 + j], bN = bhh[512 + j];
  float hprev[4];
  #pragma unroll
  for (int i = 0; i < 4; i++)
    hprev[i] = hcarry[(size_t)(b0 + q*4 + i)*256 + j];

  const _Float16* WR = Wf + (size_t)(w)      *4096;
  const _Float16* WZ = Wf + (size_t)(16 + w) *4096;
  const _Float16* WN = Wf + (size_t)(32 + w) *4096;
  const int wr_off = (j >> 5)*512 + (((j >> 3) & 3)*16)*8 + (j & 7);

  __syncthreads();
  int cur = 0;
  for (int t = 0; t < Csteps; t++) {
    const _Float16* gp = gi + (size_t)t*196608 + (size_t)b0*768 + j;
    float gR[4], gZ[4], gN[4];
    #pragma unroll
    for (int i = 0; i < 4; i++) {
      int bo = (q*4 + i)*768;
      gR[i] = (float)gp[bo];
      gZ[i] = (float)gp[bo + 256];
      gN[i] = (float)gp[bo + 512];
    }

    f32x4 aR = (f32x4){0.f,0.f,0.f,0.f};
    f32x4 aZ = (f32x4){0.f,0.f,0.f,0.f};
    f32x4 aN = (f32x4){0.f,0.f,0.f,0.f};
    #pragma unroll
    for (int kb = 0; kb < 8; kb++) {
      half8 a = *(const half8*)&hl[cur][kb*512 + l*8];
      aR = MFMA_F16(a, *(const half8*)&WR[(kb*64 + l)*8], aR, 0, 0, 0);
      aZ = MFMA_F16(a, *(const half8*)&WZ[(kb*64 + l)*8], aZ, 0, 0, 0);
      aN = MFMA_F16(a, *(const half8*)&WN[(kb*64 + l)*8], aN, 0, 0, 0);
    }

    const int nxt = cur ^ 1;
    #pragma unroll
    for (int i = 0; i < 4; i++) {
      float r  = sigm_f(aR[i] + bR + gR[i]);
      float z  = sigm_f(aZ[i] + bZ + gZ[i]);
      float nn = tanh_fast(gN[i] + r*(aN[i] + bN));
      float hp = nn + z*(hprev[i] - nn);        // (1-z)*n + z*h
      hprev[i] = hp;
      _Float16 hh = (_Float16)hp;
      hl[nxt][wr_off + (q*4 + i)*8] = hh;
      if (hseq)
        hseq[((size_t)t*256 + b0 + q*4 + i)*256 + j] = hh;
    }
    __syncthreads();
    cur ^= 1;
  }

  #pragma unroll
  for (int i = 0; i < 4; i++)
    hcarry[(size_t)(b0 + q*4 + i)*256 + j] = hprev[i];
}

// ---------------------------------------------------------------------------
extern "C" void kernel_launch(void* const* d_in, const int* in_sizes, int n_in,
                              void* d_out, int out_size, void* d_ws, size_t ws_size,
                              hipStream_t stream)
{
  const float* x     = (const float*)d_in[0];
  const float* h1_0  = (const float*)d_in[1];
  const float* h2_0  = (const float*)d_in[2];
  const float* w_ih1 = (const float*)d_in[3];
  const float* w_hh1 = (const float*)d_in[4];
  const float* b_ih1 = (const float*)d_in[5];
  const float* b_hh1 = (const float*)d_in[6];
  const float* w_ih2 = (const float*)d_in[7];
  const float* w_hh2 = (const float*)d_in[8];
  const float* b_ih2 = (const float*)d_in[9];
  const float* b_hh2 = (const float*)d_in[10];

  char* ws = (char*)d_ws;
  size_t off = 0;
  auto alloc = [&](size_t bytes) -> void* {
    void* p = ws + off; off += (bytes + 255) & ~(size_t)255; return p;
  };
  int*      slots   = (int*)     alloc(16);
  _Float16* wf_ih1  = (_Float16*)alloc(196608*2);
  _Float16* wf_hh1  = (_Float16*)alloc(196608*2);
  _Float16* wf_ih2  = (_Float16*)alloc(196608*2);
  _Float16* wf_hh2  = (_Float16*)alloc(196608*2);
  float*    hc1     = (float*)   alloc(256*256*4);
  float*    hc2     = (float*)   alloc(256*256*4);

  // choose chunk size C (steps) so gi1+gi2+h1seq chunk buffers fit in ws
  size_t fixed = off;
  int C = 512;
  while (C > 4 && fixed + (size_t)C*917504 + 1024 > ws_size) C >>= 1;
  _Float16* gi1   = (_Float16*)alloc((size_t)C*393216);
  _Float16* gi2   = (_Float16*)alloc((size_t)C*393216);
  _Float16* h1seq = (_Float16*)alloc((size_t)C*131072);
  const int nchunks = 512 / C;

  k_maxabs<<<128, 256, 0, stream>>>(w_ih1, w_hh1, w_ih2, w_hh2, 196608, slots);
  k_quant <<<3072, 256, 0, stream>>>(w_ih1, w_hh1, w_ih2, w_hh2, slots,
                                     wf_ih1, wf_hh1, wf_ih2, wf_hh2);
  (void)hipMemcpyAsync(hc1, h1_0, 256*256*4, hipMemcpyDeviceToDevice, stream);
  (void)hipMemcpyAsync(hc2, h2_0, 256*256*4, hipMemcpyDeviceToDevice, stream);

  for (int c = 0; c < nchunks; c++) {
    const float* xc = x + (size_t)c*C*65536;
    dim3 gg(C*256/64, 6);
    k_gemm<false><<<gg, 256, 0, stream>>>((const void*)xc, wf_ih1, b_ih1, gi1);
    k_gru<<<16, 1024, 0, stream>>>(gi1, wf_hh1, b_hh1, hc1, h1seq, C);
    k_gemm<true><<<gg, 256, 0, stream>>>((const void*)h1seq, wf_ih2, b_ih2, gi2);
    k_gru<<<16, 1024, 0, stream>>>(gi2, wf_hh2, b_hh2, hc2, (_Float16*)nullptr, C);
  }

  (void)hipMemcpyAsync(d_out, hc2, 256*256*4, hipMemcpyDeviceToDevice, stream);
}

// Round 3
// 3276.348 us; speedup vs baseline: 1.2045x; 1.2045x over previous
//
#include <hip/hip_runtime.h>
#include <hip/hip_fp16.h>
#include <cstdint>

typedef _Float16 half8 __attribute__((ext_vector_type(8)));
typedef float f32x4 __attribute__((ext_vector_type(4)));

#define MFMA_F16 __builtin_amdgcn_mfma_f32_16x16x32_f16

__device__ __forceinline__ float fast_rcp(float x){
#if __has_builtin(__builtin_amdgcn_rcpf)
  return __builtin_amdgcn_rcpf(x);
#else
  return 1.0f/x;
#endif
}
__device__ __forceinline__ float fast_exp2(float x){
#if __has_builtin(__builtin_amdgcn_exp2f)
  return __builtin_amdgcn_exp2f(x);
#else
  return exp2f(x);
#endif
}
__device__ __forceinline__ float sigm_f(float x){
  return fast_rcp(1.0f + fast_exp2(-1.44269504f*x));
}
__device__ __forceinline__ float tanh_fast(float x){
  float e = fast_exp2(-2.88539008f*x);            // e^(-2x)
  return fmaf(2.0f, fast_rcp(1.0f + e), -1.0f);   // 2/(1+e) - 1
}

// ---------------------------------------------------------------------------
// Phase A1: per-matrix max|w| (4 matrices of 768x256)
// ---------------------------------------------------------------------------
__global__ __launch_bounds__(256) void k_maxabs(
    const float* __restrict__ w0, const float* __restrict__ w1,
    const float* __restrict__ w2, const float* __restrict__ w3,
    int n, int* __restrict__ slots)
{
  const float* srcs[4] = {w0, w1, w2, w3};
  int m    = blockIdx.x >> 5;   // 32 blocks per matrix
  int part = blockIdx.x & 31;
  const float* w = srcs[m];
  float loc = 0.0f;
  for (int i = part*256 + threadIdx.x; i < n; i += 32*256)
    loc = fmaxf(loc, fabsf(w[i]));
  for (int off = 32; off; off >>= 1)
    loc = fmaxf(loc, __shfl_down(loc, off, 64));
  __shared__ float red[4];
  int wv = threadIdx.x >> 6;
  if ((threadIdx.x & 63) == 0) red[wv] = loc;
  __syncthreads();
  if (threadIdx.x == 0) {
    float mx = fmaxf(fmaxf(red[0], red[1]), fmaxf(red[2], red[3]));
    atomicMax(&slots[m], __float_as_int(mx));
  }
}

// ---------------------------------------------------------------------------
// Phase A2: fake-quantize -> fp16 in MFMA-B-fragment-swizzled layout:
//   offset = (tile*8+kb)*512 + lane*8 + j
// ---------------------------------------------------------------------------
__global__ __launch_bounds__(256) void k_quant(
    const float* __restrict__ w0, const float* __restrict__ w1,
    const float* __restrict__ w2, const float* __restrict__ w3,
    const int* __restrict__ slots,
    _Float16* __restrict__ f0, _Float16* __restrict__ f1,
    _Float16* __restrict__ f2, _Float16* __restrict__ f3)
{
  const float* srcs[4] = {w0, w1, w2, w3};
  _Float16*    dsts[4] = {f0, f1, f2, f3};
  int idx = blockIdx.x*256 + threadIdx.x;       // 0 .. 786431
  int m = idx / 196608;
  int e = idx - m*196608;
  float scale = __int_as_float(slots[m]) * (1.0f/127.0f);
  float w = srcs[m][e];
  float q = rintf(w/scale) * scale;
  int g = e >> 8, k = e & 255;
  int tile = g >> 4, kb = k >> 5;
  int lane = ((k >> 3) & 3)*16 + (g & 15);
  int off  = (tile*8 + kb)*512 + lane*8 + (k & 7);
  dsts[m][off] = (_Float16)q;
}

// ---------------------------------------------------------------------------
// Fat GEMM: out[r][g] = sum_k A[r][k] * Wq[g][k] + bias[g], fp16 out.
// ---------------------------------------------------------------------------
template<bool INF16>
__global__ __launch_bounds__(256) void k_gemm(
    const void* __restrict__ Ain, const _Float16* __restrict__ Wf,
    const float* __restrict__ bias, _Float16* __restrict__ out)
{
  __shared__ _Float16 Al[16384];                // 4 bands x 8 kb x 512 halves
  const int tid = threadIdx.x;
  const long r0 = (long)blockIdx.x * 64;
  const int by  = blockIdx.y;                   // 6 col-blocks of 128

  if (!INF16) {
    const float4* A = (const float4*)Ain;
    #pragma unroll
    for (int p = 0; p < 16; p++) {
      int n = p*256 + tid;
      int row = n >> 6, f4 = n & 63, k0 = f4*4;
      float4 v = A[(r0 + row)*64 + f4];
      int lane = ((k0 >> 3) & 3)*16 + (row & 15);
      _Float16* d = &Al[((row >> 4)*8 + (k0 >> 5))*512 + lane*8 + (k0 & 7)];
      d[0] = (_Float16)v.x; d[1] = (_Float16)v.y;
      d[2] = (_Float16)v.z; d[3] = (_Float16)v.w;
    }
  } else {
    const ushort4* A = (const ushort4*)Ain;
    #pragma unroll
    for (int p = 0; p < 16; p++) {
      int n = p*256 + tid;
      int row = n >> 6, f4 = n & 63, k0 = f4*4;
      ushort4 v = A[(r0 + row)*64 + f4];
      int lane = ((k0 >> 3) & 3)*16 + (row & 15);
      unsigned short* d = (unsigned short*)
          &Al[((row >> 4)*8 + (k0 >> 5))*512 + lane*8 + (k0 & 7)];
      d[0] = v.x; d[1] = v.y; d[2] = v.z; d[3] = v.w;
    }
  }
  __syncthreads();

  const int w = tid >> 6, l = tid & 63, q = l >> 4, c16 = l & 15;
  f32x4 acc[8];
  #pragma unroll
  for (int nt = 0; nt < 8; nt++) acc[nt] = (f32x4){0.f, 0.f, 0.f, 0.f};
  float bv[8];
  #pragma unroll
  for (int nt = 0; nt < 8; nt++) bv[nt] = bias[by*128 + nt*16 + c16];

  #pragma unroll
  for (int kb = 0; kb < 8; kb++) {
    half8 a = *(const half8*)&Al[(w*8 + kb)*512 + l*8];
    #pragma unroll
    for (int nt = 0; nt < 8; nt++) {
      half8 b = *(const half8*)&Wf[((size_t)((by*8 + nt)*8 + kb))*512 + l*8];
      acc[nt] = MFMA_F16(a, b, acc[nt], 0, 0, 0);
    }
  }

  #pragma unroll
  for (int nt = 0; nt < 8; nt++) {
    int colg = by*128 + nt*16 + c16;
    #pragma unroll
    for (int i = 0; i < 4; i++) {
      long rowg = r0 + w*16 + q*4 + i;
      out[(size_t)rowg*768 + colg] = (_Float16)(acc[nt][i] + bv[nt]);
    }
  }
}

// ---------------------------------------------------------------------------
// Serial GRU phase: 16 blocks x 1024 thr. Block owns batch rows b0..b0+15.
// R3 change: all W_hh fragments CU-resident. Per wave: WR(32) + WZ(32) +
// WN kb2..7 (24) persistent VGPRs; WN kb0..1 in LDS (32 KB). Zero per-step
// global weight traffic. LDS total 48 KB (h dbuf 16 KB + wn 32 KB).
// ---------------------------------------------------------------------------
__global__ __launch_bounds__(1024) void k_gru(
    const _Float16* __restrict__ gi, const _Float16* __restrict__ Wf,
    const float* __restrict__ bhh, float* __restrict__ hcarry,
    _Float16* __restrict__ hseq, int Csteps)
{
  __shared__ _Float16 hl[2][4096];              // 16 KB frag-ordered h (dbuf)
  __shared__ _Float16 wn_l[16384];              // 32 KB: 16 waves x 2 kb x 512
  const int tid = threadIdx.x;
  const int b0  = blockIdx.x * 16;

  { // stage initial h (f32 carry -> fp16 frags)
    int n = tid*4;
    int b = n >> 8, k = n & 255;
    float4 v = *(const float4*)&hcarry[(size_t)(b0 + b)*256 + k];
    _Float16* d = &hl[0][(k >> 5)*512 + (((k >> 3) & 3)*16 + b)*8 + (k & 7)];
    d[0] = (_Float16)v.x; d[1] = (_Float16)v.y;
    d[2] = (_Float16)v.z; d[3] = (_Float16)v.w;
  }

  const int w = tid >> 6, l = tid & 63, q = l >> 4, c16 = l & 15;
  const int j = w*16 + c16;                     // gate column owned by lane
  const float bR = bhh[j], bZ = bhh[256 + j], bN = bhh[512 + j];
  float hprev[4];
  #pragma unroll
  for (int i = 0; i < 4; i++)
    hprev[i] = hcarry[(size_t)(b0 + q*4 + i)*256 + j];

  const _Float16* WR = Wf + (size_t)(w)      *4096;
  const _Float16* WZ = Wf + (size_t)(16 + w) *4096;
  const _Float16* WN = Wf + (size_t)(32 + w) *4096;

  // ---- preload weights: WR/WZ all kb, WN kb2..7 -> registers ----
  half8 wr[8], wz[8], wn[6];
  #pragma unroll
  for (int kb = 0; kb < 8; kb++) {
    wr[kb] = *(const half8*)&WR[(kb*64 + l)*8];
    wz[kb] = *(const half8*)&WZ[(kb*64 + l)*8];
  }
  #pragma unroll
  for (int i = 0; i < 6; i++)
    wn[i] = *(const half8*)&WN[((i + 2)*64 + l)*8];
  // ---- WN kb0..1 -> LDS ----
  #pragma unroll
  for (int kb = 0; kb < 2; kb++)
    *(half8*)&wn_l[(w*2 + kb)*512 + l*8] = *(const half8*)&WN[(kb*64 + l)*8];

  const int wr_off = (j >> 5)*512 + (((j >> 3) & 3)*16)*8 + (j & 7);

  __syncthreads();
  int cur = 0;
  for (int t = 0; t < Csteps; t++) {
    const _Float16* gp = gi + (size_t)t*196608 + (size_t)b0*768 + j;
    float gR[4], gZ[4], gN[4];
    #pragma unroll
    for (int i = 0; i < 4; i++) {
      int bo = (q*4 + i)*768;
      gR[i] = (float)gp[bo];
      gZ[i] = (float)gp[bo + 256];
      gN[i] = (float)gp[bo + 512];
    }

    f32x4 aR = (f32x4){0.f,0.f,0.f,0.f};
    f32x4 aZ = (f32x4){0.f,0.f,0.f,0.f};
    f32x4 aN = (f32x4){0.f,0.f,0.f,0.f};
    #pragma unroll
    for (int kb = 0; kb < 8; kb++) {
      half8 a = *(const half8*)&hl[cur][kb*512 + l*8];
      half8 bn = (kb < 2) ? *(const half8*)&wn_l[(w*2 + kb)*512 + l*8]
                          : wn[kb - 2];
      aR = MFMA_F16(a, wr[kb], aR, 0, 0, 0);
      aZ = MFMA_F16(a, wz[kb], aZ, 0, 0, 0);
      aN = MFMA_F16(a, bn,     aN, 0, 0, 0);
    }

    const int nxt = cur ^ 1;
    #pragma unroll
    for (int i = 0; i < 4; i++) {
      float r  = sigm_f(aR[i] + bR + gR[i]);
      float z  = sigm_f(aZ[i] + bZ + gZ[i]);
      float nn = tanh_fast(gN[i] + r*(aN[i] + bN));
      float hp = nn + z*(hprev[i] - nn);        // (1-z)*n + z*h
      hprev[i] = hp;
      _Float16 hh = (_Float16)hp;
      hl[nxt][wr_off + (q*4 + i)*8] = hh;
      if (hseq)
        hseq[((size_t)t*256 + b0 + q*4 + i)*256 + j] = hh;
    }
    __syncthreads();
    cur ^= 1;
  }

  #pragma unroll
  for (int i = 0; i < 4; i++)
    hcarry[(size_t)(b0 + q*4 + i)*256 + j] = hprev[i];
}

// ---------------------------------------------------------------------------
extern "C" void kernel_launch(void* const* d_in, const int* in_sizes, int n_in,
                              void* d_out, int out_size, void* d_ws, size_t ws_size,
                              hipStream_t stream)
{
  const float* x     = (const float*)d_in[0];
  const float* h1_0  = (const float*)d_in[1];
  const float* h2_0  = (const float*)d_in[2];
  const float* w_ih1 = (const float*)d_in[3];
  const float* w_hh1 = (const float*)d_in[4];
  const float* b_ih1 = (const float*)d_in[5];
  const float* b_hh1 = (const float*)d_in[6];
  const float* w_ih2 = (const float*)d_in[7];
  const float* w_hh2 = (const float*)d_in[8];
  const float* b_ih2 = (const float*)d_in[9];
  const float* b_hh2 = (const float*)d_in[10];

  char* ws = (char*)d_ws;
  size_t off = 0;
  auto alloc = [&](size_t bytes) -> void* {
    void* p = ws + off; off += (bytes + 255) & ~(size_t)255; return p;
  };
  int*      slots   = (int*)     alloc(16);
  _Float16* wf_ih1  = (_Float16*)alloc(196608*2);
  _Float16* wf_hh1  = (_Float16*)alloc(196608*2);
  _Float16* wf_ih2  = (_Float16*)alloc(196608*2);
  _Float16* wf_hh2  = (_Float16*)alloc(196608*2);
  float*    hc1     = (float*)   alloc(256*256*4);
  float*    hc2     = (float*)   alloc(256*256*4);

  size_t fixed = off;
  int C = 512;
  while (C > 4 && fixed + (size_t)C*917504 + 1024 > ws_size) C >>= 1;
  _Float16* gi1   = (_Float16*)alloc((size_t)C*393216);
  _Float16* gi2   = (_Float16*)alloc((size_t)C*393216);
  _Float16* h1seq = (_Float16*)alloc((size_t)C*131072);
  const int nchunks = 512 / C;

  k_maxabs<<<128, 256, 0, stream>>>(w_ih1, w_hh1, w_ih2, w_hh2, 196608, slots);
  k_quant <<<3072, 256, 0, stream>>>(w_ih1, w_hh1, w_ih2, w_hh2, slots,
                                     wf_ih1, wf_hh1, wf_ih2, wf_hh2);
  (void)hipMemcpyAsync(hc1, h1_0, 256*256*4, hipMemcpyDeviceToDevice, stream);
  (void)hipMemcpyAsync(hc2, h2_0, 256*256*4, hipMemcpyDeviceToDevice, stream);

  for (int c = 0; c < nchunks; c++) {
    const float* xc = x + (size_t)c*C*65536;
    dim3 gg(C*256/64, 6);
    k_gemm<false><<<gg, 256, 0, stream>>>((const void*)xc, wf_ih1, b_ih1, gi1);
    k_gru<<<16, 1024, 0, stream>>>(gi1, wf_hh1, b_hh1, hc1, h1seq, C);
    k_gemm<true><<<gg, 256, 0, stream>>>((const void*)h1seq, wf_ih2, b_ih2, gi2);
    k_gru<<<16, 1024, 0, stream>>>(gi2, wf_hh2, b_hh2, hc2, (_Float16*)nullptr, C);
  }

  (void)hipMemcpyAsync(d_out, hc2, 256*256*4, hipMemcpyDeviceToDevice, stream);
}

// Round 4
// 2942.764 us; speedup vs baseline: 1.3411x; 1.1134x over previous
//
#include <hip/hip_runtime.h>
#include <hip/hip_fp16.h>
#include <cstdint>

typedef _Float16 half8 __attribute__((ext_vector_type(8)));
typedef _Float16 half4 __attribute__((ext_vector_type(4)));
typedef float f32x4 __attribute__((ext_vector_type(4)));

#define MFMA_F16 __builtin_amdgcn_mfma_f32_16x16x32_f16

__device__ __forceinline__ float fast_rcp(float x){
#if __has_builtin(__builtin_amdgcn_rcpf)
  return __builtin_amdgcn_rcpf(x);
#else
  return 1.0f/x;
#endif
}
__device__ __forceinline__ float fast_exp2(float x){
#if __has_builtin(__builtin_amdgcn_exp2f)
  return __builtin_amdgcn_exp2f(x);
#else
  return exp2f(x);
#endif
}
__device__ __forceinline__ float sigm_f(float x){
  return fast_rcp(1.0f + fast_exp2(-1.44269504f*x));
}
__device__ __forceinline__ float tanh_fast(float x){
  float e = fast_exp2(-2.88539008f*x);            // e^(-2x)
  return fmaf(2.0f, fast_rcp(1.0f + e), -1.0f);   // 2/(1+e) - 1
}

// ---------------------------------------------------------------------------
// Phase A1: per-matrix max|w| (4 matrices of 768x256)
// ---------------------------------------------------------------------------
__global__ __launch_bounds__(256) void k_maxabs(
    const float* __restrict__ w0, const float* __restrict__ w1,
    const float* __restrict__ w2, const float* __restrict__ w3,
    int n, int* __restrict__ slots)
{
  const float* srcs[4] = {w0, w1, w2, w3};
  int m    = blockIdx.x >> 5;   // 32 blocks per matrix
  int part = blockIdx.x & 31;
  const float* w = srcs[m];
  float loc = 0.0f;
  for (int i = part*256 + threadIdx.x; i < n; i += 32*256)
    loc = fmaxf(loc, fabsf(w[i]));
  for (int off = 32; off; off >>= 1)
    loc = fmaxf(loc, __shfl_down(loc, off, 64));
  __shared__ float red[4];
  int wv = threadIdx.x >> 6;
  if ((threadIdx.x & 63) == 0) red[wv] = loc;
  __syncthreads();
  if (threadIdx.x == 0) {
    float mx = fmaxf(fmaxf(red[0], red[1]), fmaxf(red[2], red[3]));
    atomicMax(&slots[m], __float_as_int(mx));
  }
}

// ---------------------------------------------------------------------------
// Phase A2: fake-quantize -> fp16 in MFMA-B-fragment-swizzled layout:
//   offset = (tile*8+kb)*512 + lane*8 + j
// ---------------------------------------------------------------------------
__global__ __launch_bounds__(256) void k_quant(
    const float* __restrict__ w0, const float* __restrict__ w1,
    const float* __restrict__ w2, const float* __restrict__ w3,
    const int* __restrict__ slots,
    _Float16* __restrict__ f0, _Float16* __restrict__ f1,
    _Float16* __restrict__ f2, _Float16* __restrict__ f3)
{
  const float* srcs[4] = {w0, w1, w2, w3};
  _Float16*    dsts[4] = {f0, f1, f2, f3};
  int idx = blockIdx.x*256 + threadIdx.x;       // 0 .. 786431
  int m = idx / 196608;
  int e = idx - m*196608;
  float scale = __int_as_float(slots[m]) * (1.0f/127.0f);
  float w = srcs[m][e];
  float q = rintf(w/scale) * scale;
  int g = e >> 8, k = e & 255;
  int tile = g >> 4, kb = k >> 5;
  int lane = ((k >> 3) & 3)*16 + (g & 15);
  int off  = (tile*8 + kb)*512 + lane*8 + (k & 7);
  dsts[m][off] = (_Float16)q;
}

// ---------------------------------------------------------------------------
// gi layout (consumer-ordered, packed):
//   element (t, gate g, col j, batch b):
//   jw=j>>4, c=j&15, bb=b>>4, q=(b>>2)&3, i=b&3
//   off = (((t*3+g)*16 + jw)*16 + bb)*256 + (q*16+c)*4 + i
// Consumer wave w in gru block bb reads 512B contiguous per gate: off = l*4.
// ---------------------------------------------------------------------------

// Fat GEMM (f32 A = x): gi[...] = x @ Wq^T + bias, written in gi layout.
__global__ __launch_bounds__(256) void k_gemm_f32(
    const float* __restrict__ A, const _Float16* __restrict__ Wf,
    const float* __restrict__ bias, _Float16* __restrict__ gi)
{
  __shared__ _Float16 Al[16384];                // 4 bands x 8 kb x 512 halves
  const int tid = threadIdx.x;
  const long r0 = (long)blockIdx.x * 64;
  const int by  = blockIdx.y;                   // 6 col-blocks of 128

  const float4* A4 = (const float4*)A;
  #pragma unroll
  for (int p = 0; p < 16; p++) {
    int n = p*256 + tid;
    int row = n >> 6, f4 = n & 63, k0 = f4*4;
    float4 v = A4[(r0 + row)*64 + f4];
    int lane = ((k0 >> 3) & 3)*16 + (row & 15);
    _Float16* d = &Al[((row >> 4)*8 + (k0 >> 5))*512 + lane*8 + (k0 & 7)];
    d[0] = (_Float16)v.x; d[1] = (_Float16)v.y;
    d[2] = (_Float16)v.z; d[3] = (_Float16)v.w;
  }
  __syncthreads();

  const int w = tid >> 6, l = tid & 63, c16 = l & 15;
  f32x4 acc[8];
  #pragma unroll
  for (int nt = 0; nt < 8; nt++) acc[nt] = (f32x4){0.f, 0.f, 0.f, 0.f};
  float bv[8];
  #pragma unroll
  for (int nt = 0; nt < 8; nt++) bv[nt] = bias[by*128 + nt*16 + c16];

  #pragma unroll
  for (int kb = 0; kb < 8; kb++) {
    half8 a = *(const half8*)&Al[(w*8 + kb)*512 + l*8];
    #pragma unroll
    for (int nt = 0; nt < 8; nt++) {
      half8 b = *(const half8*)&Wf[((size_t)((by*8 + nt)*8 + kb))*512 + l*8];
      acc[nt] = MFMA_F16(a, b, acc[nt], 0, 0, 0);
    }
  }

  const int t = (int)(r0 >> 8);
  const int bb = ((int)(r0 & 255) >> 4) + w;
  #pragma unroll
  for (int nt = 0; nt < 8; nt++) {
    int cj = by*8 + nt;                         // 16-col group index (0..47)
    int g  = cj >> 4, jw = cj & 15;
    size_t chunk = ((size_t)(t*3 + g)*16 + jw)*16 + bb;
    half4 v;
    #pragma unroll
    for (int i = 0; i < 4; i++) v[i] = (_Float16)(acc[nt][i] + bv[nt]);
    *(half4*)&gi[chunk*256 + l*4] = v;
  }
}

// Fat GEMM (A = hseq in frag layout): direct A-frag global loads, no LDS.
__global__ __launch_bounds__(256) void k_gemm_h(
    const _Float16* __restrict__ hseq, const _Float16* __restrict__ Wf,
    const float* __restrict__ bias, _Float16* __restrict__ gi)
{
  const int tid = threadIdx.x;
  const long r0 = (long)blockIdx.x * 64;
  const int by  = blockIdx.y;

  const int w = tid >> 6, l = tid & 63, c16 = l & 15;
  const int t = (int)(r0 >> 8);
  const int bb = ((int)(r0 & 255) >> 4) + w;

  f32x4 acc[8];
  #pragma unroll
  for (int nt = 0; nt < 8; nt++) acc[nt] = (f32x4){0.f, 0.f, 0.f, 0.f};
  float bv[8];
  #pragma unroll
  for (int nt = 0; nt < 8; nt++) bv[nt] = bias[by*128 + nt*16 + c16];

  #pragma unroll
  for (int kb = 0; kb < 8; kb++) {
    half8 a = *(const half8*)&hseq[(((size_t)t*16 + bb)*8 + kb)*512 + l*8];
    #pragma unroll
    for (int nt = 0; nt < 8; nt++) {
      half8 b = *(const half8*)&Wf[((size_t)((by*8 + nt)*8 + kb))*512 + l*8];
      acc[nt] = MFMA_F16(a, b, acc[nt], 0, 0, 0);
    }
  }

  #pragma unroll
  for (int nt = 0; nt < 8; nt++) {
    int cj = by*8 + nt;
    int g  = cj >> 4, jw = cj & 15;
    size_t chunk = ((size_t)(t*3 + g)*16 + jw)*16 + bb;
    half4 v;
    #pragma unroll
    for (int i = 0; i < 4; i++) v[i] = (_Float16)(acc[nt][i] + bv[nt]);
    *(half4*)&gi[chunk*256 + l*4] = v;
  }
}

// ---------------------------------------------------------------------------
// Serial GRU: 16 blocks x 1024 thr, __launch_bounds__(1024,4) -> 128 VGPR cap.
// Weights CU-resident: WR(32)+WZ(32)+WN kb3..7(20) = 84 VGPRs/wave;
// WN kb0..2 in LDS (48 KB). h double-buffer 16 KB. LDS = 64 KB exactly.
// gi: packed consumer layout (3x half4/lane/step, coalesced).
// hseq: frag-layout dump (1x half4/lane/step, coalesced) after barrier.
// ---------------------------------------------------------------------------
__global__ __launch_bounds__(1024, 4) void k_gru(
    const _Float16* __restrict__ gi, const _Float16* __restrict__ Wf,
    const float* __restrict__ bhh, float* __restrict__ hcarry,
    _Float16* __restrict__ hseq, int Csteps)
{
  __shared__ _Float16 hl[2][4096];              // 16 KB frag-ordered h (dbuf)
  __shared__ _Float16 wn_l[24576];              // 48 KB: 16 waves x 3 kb x 512
  const int tid = threadIdx.x;
  const int bb  = blockIdx.x;
  const int b0  = bb * 16;

  { // stage initial h (f32 carry -> fp16 frags)
    int n = tid*4;
    int b = n >> 8, k = n & 255;
    float4 v = *(const float4*)&hcarry[(size_t)(b0 + b)*256 + k];
    _Float16* d = &hl[0][(k >> 5)*512 + (((k >> 3) & 3)*16 + b)*8 + (k & 7)];
    d[0] = (_Float16)v.x; d[1] = (_Float16)v.y;
    d[2] = (_Float16)v.z; d[3] = (_Float16)v.w;
  }

  const int w = tid >> 6, l = tid & 63, q = l >> 4, c16 = l & 15;
  const int j = w*16 + c16;                     // gate column owned by lane
  const float bR = bhh[j], bZ = bhh[256 + j], bN = bhh[512 + j];
  float hprev[4];
  #pragma unroll
  for (int i = 0; i < 4; i++)
    hprev[i] = hcarry[(size_t)(b0 + q*4 + i)*256 + j];

  const _Float16* WR = Wf + (size_t)(w)      *4096;
  const _Float16* WZ = Wf + (size_t)(16 + w) *4096;
  const _Float16* WN = Wf + (size_t)(32 + w) *4096;

  // ---- preload: WR/WZ all kb, WN kb3..7 -> registers; WN kb0..2 -> LDS ----
  half8 wr[8], wz[8], wn[5];
  #pragma unroll
  for (int kb = 0; kb < 8; kb++) {
    wr[kb] = *(const half8*)&WR[(kb*64 + l)*8];
    wz[kb] = *(const half8*)&WZ[(kb*64 + l)*8];
  }
  #pragma unroll
  for (int i = 0; i < 5; i++)
    wn[i] = *(const half8*)&WN[((i + 3)*64 + l)*8];
  #pragma unroll
  for (int kb = 0; kb < 3; kb++)
    *(half8*)&wn_l[(w*3 + kb)*512 + l*8] = *(const half8*)&WN[(kb*64 + l)*8];

  const int wr_off = (j >> 5)*512 + ((j >> 3) & 3)*128 + (j & 7);
  const _Float16* gbase = gi + ((size_t)(w*16 + bb))*256 + l*4;

  __syncthreads();
  int cur = 0;
  for (int t = 0; t < Csteps; t++) {
    const _Float16* gp = gbase + (size_t)t*196608;
    half4 vR = *(const half4*)(gp);
    half4 vZ = *(const half4*)(gp + 65536);
    half4 vN = *(const half4*)(gp + 131072);

    f32x4 aR = (f32x4){0.f,0.f,0.f,0.f};
    f32x4 aZ = (f32x4){0.f,0.f,0.f,0.f};
    f32x4 aN = (f32x4){0.f,0.f,0.f,0.f};
    #pragma unroll
    for (int kb = 0; kb < 8; kb++) {
      half8 a = *(const half8*)&hl[cur][kb*512 + l*8];
      half8 bn = (kb < 3) ? *(const half8*)&wn_l[(w*3 + kb)*512 + l*8]
                          : wn[kb - 3];
      aR = MFMA_F16(a, wr[kb], aR, 0, 0, 0);
      aZ = MFMA_F16(a, wz[kb], aZ, 0, 0, 0);
      aN = MFMA_F16(a, bn,     aN, 0, 0, 0);
    }

    const int nxt = cur ^ 1;
    #pragma unroll
    for (int i = 0; i < 4; i++) {
      float r  = sigm_f(aR[i] + bR + (float)vR[i]);
      float z  = sigm_f(aZ[i] + bZ + (float)vZ[i]);
      float nn = tanh_fast((float)vN[i] + r*(aN[i] + bN));
      float hp = nn + z*(hprev[i] - nn);        // (1-z)*n + z*h
      hprev[i] = hp;
      hl[nxt][wr_off + (q*4 + i)*8] = (_Float16)hp;
    }
    __syncthreads();
    if (hseq)
      *(half4*)&hseq[((size_t)t*16 + bb)*4096 + tid*4] =
          *(const half4*)&hl[nxt][tid*4];
    cur ^= 1;
  }

  #pragma unroll
  for (int i = 0; i < 4; i++)
    hcarry[(size_t)(b0 + q*4 + i)*256 + j] = hprev[i];
}

// ---------------------------------------------------------------------------
extern "C" void kernel_launch(void* const* d_in, const int* in_sizes, int n_in,
                              void* d_out, int out_size, void* d_ws, size_t ws_size,
                              hipStream_t stream)
{
  const float* x     = (const float*)d_in[0];
  const float* h1_0  = (const float*)d_in[1];
  const float* h2_0  = (const float*)d_in[2];
  const float* w_ih1 = (const float*)d_in[3];
  const float* w_hh1 = (const float*)d_in[4];
  const float* b_ih1 = (const float*)d_in[5];
  const float* b_hh1 = (const float*)d_in[6];
  const float* w_ih2 = (const float*)d_in[7];
  const float* w_hh2 = (const float*)d_in[8];
  const float* b_ih2 = (const float*)d_in[9];
  const float* b_hh2 = (const float*)d_in[10];

  char* ws = (char*)d_ws;
  size_t off = 0;
  auto alloc = [&](size_t bytes) -> void* {
    void* p = ws + off; off += (bytes + 255) & ~(size_t)255; return p;
  };
  int*      slots   = (int*)     alloc(16);
  _Float16* wf_ih1  = (_Float16*)alloc(196608*2);
  _Float16* wf_hh1  = (_Float16*)alloc(196608*2);
  _Float16* wf_ih2  = (_Float16*)alloc(196608*2);
  _Float16* wf_hh2  = (_Float16*)alloc(196608*2);
  float*    hc1     = (float*)   alloc(256*256*4);
  float*    hc2     = (float*)   alloc(256*256*4);

  size_t fixed = off;
  int C = 512;
  while (C > 4 && fixed + (size_t)C*917504 + 1024 > ws_size) C >>= 1;
  _Float16* gi1   = (_Float16*)alloc((size_t)C*393216);
  _Float16* gi2   = (_Float16*)alloc((size_t)C*393216);
  _Float16* h1seq = (_Float16*)alloc((size_t)C*131072);
  const int nchunks = 512 / C;

  k_maxabs<<<128, 256, 0, stream>>>(w_ih1, w_hh1, w_ih2, w_hh2, 196608, slots);
  k_quant <<<3072, 256, 0, stream>>>(w_ih1, w_hh1, w_ih2, w_hh2, slots,
                                     wf_ih1, wf_hh1, wf_ih2, wf_hh2);
  (void)hipMemcpyAsync(hc1, h1_0, 256*256*4, hipMemcpyDeviceToDevice, stream);
  (void)hipMemcpyAsync(hc2, h2_0, 256*256*4, hipMemcpyDeviceToDevice, stream);

  for (int c = 0; c < nchunks; c++) {
    const float* xc = x + (size_t)c*C*65536;
    dim3 gg(C*256/64, 6);
    k_gemm_f32<<<gg, 256, 0, stream>>>(xc, wf_ih1, b_ih1, gi1);
    k_gru<<<16, 1024, 0, stream>>>(gi1, wf_hh1, b_hh1, hc1, h1seq, C);
    k_gemm_h<<<gg, 256, 0, stream>>>(h1seq, wf_ih2, b_ih2, gi2);
    k_gru<<<16, 1024, 0, stream>>>(gi2, wf_hh2, b_hh2, hc2, (_Float16*)nullptr, C);
  }

  (void)hipMemcpyAsync(d_out, hc2, 256*256*4, hipMemcpyDeviceToDevice, stream);
}

// Round 5
// 2701.974 us; speedup vs baseline: 1.4606x; 1.0891x over previous
//
#include <hip/hip_runtime.h>
#include <hip/hip_fp16.h>
#include <cstdint>

typedef _Float16 half8 __attribute__((ext_vector_type(8)));
typedef _Float16 half4 __attribute__((ext_vector_type(4)));
typedef float f32x4 __attribute__((ext_vector_type(4)));

#define MFMA_F16 __builtin_amdgcn_mfma_f32_16x16x32_f16
#define PIN(x) asm volatile("" : "+v"(x))

__device__ __forceinline__ float fast_rcp(float x){
#if __has_builtin(__builtin_amdgcn_rcpf)
  return __builtin_amdgcn_rcpf(x);
#else
  return 1.0f/x;
#endif
}
__device__ __forceinline__ float fast_exp2(float x){
#if __has_builtin(__builtin_amdgcn_exp2f)
  return __builtin_amdgcn_exp2f(x);
#else
  return exp2f(x);
#endif
}
__device__ __forceinline__ float sigm_f(float x){
  return fast_rcp(1.0f + fast_exp2(-1.44269504f*x));
}
__device__ __forceinline__ float tanh_fast(float x){
  float e = fast_exp2(-2.88539008f*x);            // e^(-2x)
  return fmaf(2.0f, fast_rcp(1.0f + e), -1.0f);   // 2/(1+e) - 1
}

// ---------------------------------------------------------------------------
// Phase A1: per-matrix max|w| (4 matrices of 768x256)
// ---------------------------------------------------------------------------
__global__ __launch_bounds__(256) void k_maxabs(
    const float* __restrict__ w0, const float* __restrict__ w1,
    const float* __restrict__ w2, const float* __restrict__ w3,
    int n, int* __restrict__ slots)
{
  const float* srcs[4] = {w0, w1, w2, w3};
  int m    = blockIdx.x >> 5;   // 32 blocks per matrix
  int part = blockIdx.x & 31;
  const float* w = srcs[m];
  float loc = 0.0f;
  for (int i = part*256 + threadIdx.x; i < n; i += 32*256)
    loc = fmaxf(loc, fabsf(w[i]));
  for (int off = 32; off; off >>= 1)
    loc = fmaxf(loc, __shfl_down(loc, off, 64));
  __shared__ float red[4];
  int wv = threadIdx.x >> 6;
  if ((threadIdx.x & 63) == 0) red[wv] = loc;
  __syncthreads();
  if (threadIdx.x == 0) {
    float mx = fmaxf(fmaxf(red[0], red[1]), fmaxf(red[2], red[3]));
    atomicMax(&slots[m], __float_as_int(mx));
  }
}

// ---------------------------------------------------------------------------
// Phase A2: fake-quantize -> fp16 in MFMA-B-fragment-swizzled layout:
//   offset = (tile*8+kb)*512 + lane*8 + j
// ---------------------------------------------------------------------------
__global__ __launch_bounds__(256) void k_quant(
    const float* __restrict__ w0, const float* __restrict__ w1,
    const float* __restrict__ w2, const float* __restrict__ w3,
    const int* __restrict__ slots,
    _Float16* __restrict__ f0, _Float16* __restrict__ f1,
    _Float16* __restrict__ f2, _Float16* __restrict__ f3)
{
  const float* srcs[4] = {w0, w1, w2, w3};
  _Float16*    dsts[4] = {f0, f1, f2, f3};
  int idx = blockIdx.x*256 + threadIdx.x;       // 0 .. 786431
  int m = idx / 196608;
  int e = idx - m*196608;
  float scale = __int_as_float(slots[m]) * (1.0f/127.0f);
  float w = srcs[m][e];
  float q = rintf(w/scale) * scale;
  int g = e >> 8, k = e & 255;
  int tile = g >> 4, kb = k >> 5;
  int lane = ((k >> 3) & 3)*16 + (g & 15);
  int off  = (tile*8 + kb)*512 + lane*8 + (k & 7);
  dsts[m][off] = (_Float16)q;
}

// ---------------------------------------------------------------------------
// gi layout (consumer-ordered, gate-packed):
//   chunk(t, jw, bb) = ((t*16 + jw)*16 + bb), 768 halves per chunk.
//   lane l, gate g: chunk*768 + l*12 + g*4  (half4 per gate, offsets 0/8/16 B)
// bR,bZ (= b_hh r/z) are folded into the GEMM bias; bN is NOT (sits inside
// r*(...) in the GRU n-gate).
// ---------------------------------------------------------------------------

// Fat GEMM (f32 A = x): gi = x @ Wq^T + b_ih (+ b_hh for r,z), gi layout.
__global__ __launch_bounds__(256) void k_gemm_f32(
    const float* __restrict__ A, const _Float16* __restrict__ Wf,
    const float* __restrict__ bih, const float* __restrict__ bhh,
    _Float16* __restrict__ gi)
{
  __shared__ _Float16 Al[16384];                // 4 bands x 8 kb x 512 halves
  const int tid = threadIdx.x;
  const long r0 = (long)blockIdx.x * 64;
  const int by  = blockIdx.y;                   // 6 col-blocks of 128

  const float4* A4 = (const float4*)A;
  #pragma unroll
  for (int p = 0; p < 16; p++) {
    int n = p*256 + tid;
    int row = n >> 6, f4 = n & 63, k0 = f4*4;
    float4 v = A4[(r0 + row)*64 + f4];
    int lane = ((k0 >> 3) & 3)*16 + (row & 15);
    _Float16* d = &Al[((row >> 4)*8 + (k0 >> 5))*512 + lane*8 + (k0 & 7)];
    d[0] = (_Float16)v.x; d[1] = (_Float16)v.y;
    d[2] = (_Float16)v.z; d[3] = (_Float16)v.w;
  }
  __syncthreads();

  const int w = tid >> 6, l = tid & 63, c16 = l & 15;
  f32x4 acc[8];
  #pragma unroll
  for (int nt = 0; nt < 8; nt++) acc[nt] = (f32x4){0.f, 0.f, 0.f, 0.f};
  float bv[8];
  #pragma unroll
  for (int nt = 0; nt < 8; nt++) {
    int col = by*128 + nt*16 + c16;             // 0..767
    bv[nt] = bih[col] + (col < 512 ? bhh[col] : 0.0f);
  }

  #pragma unroll
  for (int kb = 0; kb < 8; kb++) {
    half8 a = *(const half8*)&Al[(w*8 + kb)*512 + l*8];
    #pragma unroll
    for (int nt = 0; nt < 8; nt++) {
      half8 b = *(const half8*)&Wf[((size_t)((by*8 + nt)*8 + kb))*512 + l*8];
      acc[nt] = MFMA_F16(a, b, acc[nt], 0, 0, 0);
    }
  }

  const int t = (int)(r0 >> 8);
  const int bb = ((int)(r0 & 255) >> 4) + w;
  #pragma unroll
  for (int nt = 0; nt < 8; nt++) {
    int cj = by*8 + nt;                         // 16-col group index (0..47)
    int g  = cj >> 4, jw = cj & 15;
    size_t chunk = ((size_t)t*16 + jw)*16 + bb;
    half4 v;
    #pragma unroll
    for (int i = 0; i < 4; i++) v[i] = (_Float16)(acc[nt][i] + bv[nt]);
    *(half4*)&gi[chunk*768 + l*12 + g*4] = v;
  }
}

// Fat GEMM (A = hseq in frag layout): direct A-frag global loads, no LDS.
__global__ __launch_bounds__(256) void k_gemm_h(
    const _Float16* __restrict__ hseq, const _Float16* __restrict__ Wf,
    const float* __restrict__ bih, const float* __restrict__ bhh,
    _Float16* __restrict__ gi)
{
  const int tid = threadIdx.x;
  const long r0 = (long)blockIdx.x * 64;
  const int by  = blockIdx.y;

  const int w = tid >> 6, l = tid & 63, c16 = l & 15;
  const int t = (int)(r0 >> 8);
  const int bb = ((int)(r0 & 255) >> 4) + w;

  f32x4 acc[8];
  #pragma unroll
  for (int nt = 0; nt < 8; nt++) acc[nt] = (f32x4){0.f, 0.f, 0.f, 0.f};
  float bv[8];
  #pragma unroll
  for (int nt = 0; nt < 8; nt++) {
    int col = by*128 + nt*16 + c16;
    bv[nt] = bih[col] + (col < 512 ? bhh[col] : 0.0f);
  }

  #pragma unroll
  for (int kb = 0; kb < 8; kb++) {
    half8 a = *(const half8*)&hseq[(((size_t)t*16 + bb)*8 + kb)*512 + l*8];
    #pragma unroll
    for (int nt = 0; nt < 8; nt++) {
      half8 b = *(const half8*)&Wf[((size_t)((by*8 + nt)*8 + kb))*512 + l*8];
      acc[nt] = MFMA_F16(a, b, acc[nt], 0, 0, 0);
    }
  }

  #pragma unroll
  for (int nt = 0; nt < 8; nt++) {
    int cj = by*8 + nt;
    int g  = cj >> 4, jw = cj & 15;
    size_t chunk = ((size_t)t*16 + jw)*16 + bb;
    half4 v;
    #pragma unroll
    for (int i = 0; i < 4; i++) v[i] = (_Float16)(acc[nt][i] + bv[nt]);
    *(half4*)&gi[chunk*768 + l*12 + g*4] = v;
  }
}

// ---------------------------------------------------------------------------
// Serial GRU: 16 blocks x 1024 thr, __launch_bounds__(1024,4) -> 128 VGPR cap.
// R5: weights PINNED in VGPRs via opaque asm (prevents rematerialization):
// WR(32)+WZ(32)+WN kb3..7(20) = 84 pinned; WN kb0..2 in LDS (48 KB).
// gi gate-packed: 3x half4 off ONE address reg (imm offsets 0/8/16).
// ---------------------------------------------------------------------------
__global__ __launch_bounds__(1024, 4) void k_gru(
    const _Float16* __restrict__ gi, const _Float16* __restrict__ Wf,
    const float* __restrict__ bhh, float* __restrict__ hcarry,
    _Float16* __restrict__ hseq, int Csteps)
{
  __shared__ _Float16 hl[2][4096];              // 16 KB frag-ordered h (dbuf)
  __shared__ _Float16 wn_l[24576];              // 48 KB: 16 waves x 3 kb x 512
  const int tid = threadIdx.x;
  const int bb  = blockIdx.x;
  const int b0  = bb * 16;

  { // stage initial h (f32 carry -> fp16 frags)
    int n = tid*4;
    int b = n >> 8, k = n & 255;
    float4 v = *(const float4*)&hcarry[(size_t)(b0 + b)*256 + k];
    _Float16* d = &hl[0][(k >> 5)*512 + (((k >> 3) & 3)*16 + b)*8 + (k & 7)];
    d[0] = (_Float16)v.x; d[1] = (_Float16)v.y;
    d[2] = (_Float16)v.z; d[3] = (_Float16)v.w;
  }

  const int w = tid >> 6, l = tid & 63, q = l >> 4, c16 = l & 15;
  const int j = w*16 + c16;                     // gate column owned by lane
  const float bN = bhh[512 + j];
  float hprev[4];
  #pragma unroll
  for (int i = 0; i < 4; i++)
    hprev[i] = hcarry[(size_t)(b0 + q*4 + i)*256 + j];

  const _Float16* WR = Wf + (size_t)(w)      *4096;
  const _Float16* WZ = Wf + (size_t)(16 + w) *4096;
  const _Float16* WN = Wf + (size_t)(32 + w) *4096;

  // ---- preload + PIN: WR/WZ all kb, WN kb3..7 -> regs; WN kb0..2 -> LDS ----
  half8 wr[8], wz[8], wn[5];
  #pragma unroll
  for (int kb = 0; kb < 8; kb++) {
    wr[kb] = *(const half8*)&WR[(kb*64 + l)*8];  PIN(wr[kb]);
    wz[kb] = *(const half8*)&WZ[(kb*64 + l)*8];  PIN(wz[kb]);
  }
  #pragma unroll
  for (int i = 0; i < 5; i++) {
    wn[i] = *(const half8*)&WN[((i + 3)*64 + l)*8];  PIN(wn[i]);
  }
  #pragma unroll
  for (int kb = 0; kb < 3; kb++)
    *(half8*)&wn_l[(w*3 + kb)*512 + l*8] = *(const half8*)&WN[(kb*64 + l)*8];

  const int wr_off = (j >> 5)*512 + ((j >> 3) & 3)*128 + (j & 7);
  const _Float16* gp = gi + ((size_t)(w*16 + bb))*768 + l*12;
  _Float16* hq = hseq ? hseq + (size_t)bb*4096 + tid*4 : (_Float16*)nullptr;

  __syncthreads();
  int cur = 0;
  for (int t = 0; t < Csteps; t++) {
    half4 vR = *(const half4*)(gp);
    half4 vZ = *(const half4*)(gp + 4);
    half4 vN = *(const half4*)(gp + 8);
    gp += 196608;

    f32x4 aR = (f32x4){0.f,0.f,0.f,0.f};
    f32x4 aZ = (f32x4){0.f,0.f,0.f,0.f};
    f32x4 aN = (f32x4){0.f,0.f,0.f,0.f};
    #pragma unroll
    for (int kb = 0; kb < 8; kb++) {
      half8 a = *(const half8*)&hl[cur][kb*512 + l*8];
      half8 bn = (kb < 3) ? *(const half8*)&wn_l[(w*3 + kb)*512 + l*8]
                          : wn[kb - 3];
      aR = MFMA_F16(a, wr[kb], aR, 0, 0, 0);
      aZ = MFMA_F16(a, wz[kb], aZ, 0, 0, 0);
      aN = MFMA_F16(a, bn,     aN, 0, 0, 0);
    }

    const int nxt = cur ^ 1;
    #pragma unroll
    for (int i = 0; i < 4; i++) {
      float r  = sigm_f(aR[i] + (float)vR[i]);
      float z  = sigm_f(aZ[i] + (float)vZ[i]);
      float nn = tanh_fast((float)vN[i] + r*(aN[i] + bN));
      float hp = nn + z*(hprev[i] - nn);        // (1-z)*n + z*h
      hprev[i] = hp;
      hl[nxt][wr_off + (q*4 + i)*8] = (_Float16)hp;
    }
    __syncthreads();
    if (hq) {
      *(half4*)hq = *(const half4*)&hl[nxt][tid*4];
      hq += 65536;
    }
    cur ^= 1;
  }

  #pragma unroll
  for (int i = 0; i < 4; i++)
    hcarry[(size_t)(b0 + q*4 + i)*256 + j] = hprev[i];
}

// ---------------------------------------------------------------------------
extern "C" void kernel_launch(void* const* d_in, const int* in_sizes, int n_in,
                              void* d_out, int out_size, void* d_ws, size_t ws_size,
                              hipStream_t stream)
{
  const float* x     = (const float*)d_in[0];
  const float* h1_0  = (const float*)d_in[1];
  const float* h2_0  = (const float*)d_in[2];
  const float* w_ih1 = (const float*)d_in[3];
  const float* w_hh1 = (const float*)d_in[4];
  const float* b_ih1 = (const float*)d_in[5];
  const float* b_hh1 = (const float*)d_in[6];
  const float* w_ih2 = (const float*)d_in[7];
  const float* w_hh2 = (const float*)d_in[8];
  const float* b_ih2 = (const float*)d_in[9];
  const float* b_hh2 = (const float*)d_in[10];

  char* ws = (char*)d_ws;
  size_t off = 0;
  auto alloc = [&](size_t bytes) -> void* {
    void* p = ws + off; off += (bytes + 255) & ~(size_t)255; return p;
  };
  int*      slots   = (int*)     alloc(16);
  _Float16* wf_ih1  = (_Float16*)alloc(196608*2);
  _Float16* wf_hh1  = (_Float16*)alloc(196608*2);
  _Float16* wf_ih2  = (_Float16*)alloc(196608*2);
  _Float16* wf_hh2  = (_Float16*)alloc(196608*2);
  float*    hc1     = (float*)   alloc(256*256*4);
  float*    hc2     = (float*)   alloc(256*256*4);

  size_t fixed = off;
  int C = 512;
  while (C > 4 && fixed + (size_t)C*917504 + 1024 > ws_size) C >>= 1;
  _Float16* gi1   = (_Float16*)alloc((size_t)C*393216);
  _Float16* gi2   = (_Float16*)alloc((size_t)C*393216);
  _Float16* h1seq = (_Float16*)alloc((size_t)C*131072);
  const int nchunks = 512 / C;

  k_maxabs<<<128, 256, 0, stream>>>(w_ih1, w_hh1, w_ih2, w_hh2, 196608, slots);
  k_quant <<<3072, 256, 0, stream>>>(w_ih1, w_hh1, w_ih2, w_hh2, slots,
                                     wf_ih1, wf_hh1, wf_ih2, wf_hh2);
  (void)hipMemcpyAsync(hc1, h1_0, 256*256*4, hipMemcpyDeviceToDevice, stream);
  (void)hipMemcpyAsync(hc2, h2_0, 256*256*4, hipMemcpyDeviceToDevice, stream);

  for (int c = 0; c < nchunks; c++) {
    const float* xc = x + (size_t)c*C*65536;
    dim3 gg(C*256/64, 6);
    k_gemm_f32<<<gg, 256, 0, stream>>>(xc, wf_ih1, b_ih1, b_hh1, gi1);
    k_gru<<<16, 1024, 0, stream>>>(gi1, wf_hh1, b_hh1, hc1, h1seq, C);
    k_gemm_h<<<gg, 256, 0, stream>>>(h1seq, wf_ih2, b_ih2, b_hh2, gi2);
    k_gru<<<16, 1024, 0, stream>>>(gi2, wf_hh2, b_hh2, hc2, (_Float16*)nullptr, C);
  }

  (void)hipMemcpyAsync(d_out, hc2, 256*256*4, hipMemcpyDeviceToDevice, stream);
}